// Round 3
// baseline (910.739 us; speedup 1.0000x reference)
//
#include <hip/hip_runtime.h>

#define NN 100000
#define NE 1600000
#define NPB 128                        // nodes per bucket
#define NBUCK ((NN + NPB - 1) / NPB)   // 782
#define CAP 2560                       // max edges/bucket (mean 2048, +11 sigma)
#define PBLOCKS 128
#define EPB (NE / PBLOCKS)             // 12500

// ---------------- bucket partition: packed[b*CAP + i] = (dst&127)<<17 | src ----------------
__global__ __launch_bounds__(256) void part_kernel(const int* __restrict__ src,
                                                   const int* __restrict__ dst,
                                                   unsigned int* __restrict__ bcount,
                                                   unsigned int* __restrict__ packed) {
    __shared__ unsigned int lcnt[NBUCK];
    __shared__ unsigned int lcur[NBUCK];
    for (int i = threadIdx.x; i < NBUCK; i += 256) lcnt[i] = 0u;
    __syncthreads();
    int e0 = blockIdx.x * EPB;
    for (int e = e0 + threadIdx.x; e < e0 + EPB; e += 256)
        atomicAdd(&lcnt[((unsigned)dst[e]) >> 7], 1u);
    __syncthreads();
    for (int i = threadIdx.x; i < NBUCK; i += 256) {
        unsigned int c = lcnt[i];
        lcur[i] = c ? atomicAdd(&bcount[i], c) : 0u;  // reserve contiguous run
    }
    __syncthreads();
    for (int e = e0 + threadIdx.x; e < e0 + EPB; e += 256) {
        unsigned int d = (unsigned)dst[e];
        unsigned int b = d >> 7;
        unsigned int pos = atomicAdd(&lcur[b], 1u);   // sequential within run
        packed[(size_t)b * CAP + pos] = ((d & 127u) << 17) | (unsigned)src[e];
    }
}

// ---------------- per-bucket degree -> dinv ----------------
__global__ __launch_bounds__(256) void degdinv_kernel(const unsigned int* __restrict__ bcount,
                                                      const unsigned int* __restrict__ packed,
                                                      float* __restrict__ dinv) {
    __shared__ unsigned int cnt[NPB];
    int b = blockIdx.x;
    if (threadIdx.x < NPB) cnt[threadIdx.x] = 0u;
    __syncthreads();
    unsigned int n = bcount[b];
    const unsigned int* pk = packed + (size_t)b * CAP;
    for (unsigned int i = threadIdx.x; i < n; i += 256)
        atomicAdd(&cnt[pk[i] >> 17], 1u);
    __syncthreads();
    int node = b * NPB + threadIdx.x;
    if (threadIdx.x < NPB && node < NN)
        dinv[node] = rsqrtf((float)cnt[threadIdx.x] + 1.0f);  // +1 self-loop
}

// ---------------- embed MLP + hw1 = (h @ Wg1) * dinv ----------------
__global__ __launch_bounds__(256) void embed_kernel(
    const float* __restrict__ x, const float* __restrict__ We1, const float* __restrict__ be1,
    const float* __restrict__ We2, const float* __restrict__ be2, const float* __restrict__ Wg1,
    const float* __restrict__ dinv, float* __restrict__ hws) {
    __shared__ float sWe1[6 * 64];
    __shared__ float sbe1[64];
    __shared__ float sWe2[64 * 32];
    __shared__ float sbe2[32];
    __shared__ float sWg1[32 * 32];
    for (int i = threadIdx.x; i < 6 * 64; i += 256) sWe1[i] = We1[i];
    for (int i = threadIdx.x; i < 64; i += 256) sbe1[i] = be1[i];
    for (int i = threadIdx.x; i < 64 * 32; i += 256) sWe2[i] = We2[i];
    for (int i = threadIdx.x; i < 32; i += 256) sbe2[i] = be2[i];
    for (int i = threadIdx.x; i < 32 * 32; i += 256) sWg1[i] = Wg1[i];
    __syncthreads();

    int node = blockIdx.x * 256 + threadIdx.x;
    if (node >= NN) return;

    float xv[6];
#pragma unroll
    for (int k = 0; k < 6; k++) xv[k] = x[node * 6 + k];

    float h1[64];
#pragma unroll
    for (int j = 0; j < 64; j++) {
        float a = sbe1[j];
#pragma unroll
        for (int k = 0; k < 6; k++) a += xv[k] * sWe1[k * 64 + j];
        h1[j] = tanhf(a);
    }

    float h[32];
#pragma unroll 4
    for (int j = 0; j < 32; j++) {
        float a = sbe2[j];
#pragma unroll
        for (int k = 0; k < 64; k++) a += h1[k] * sWe2[k * 32 + j];
        h[j] = tanhf(a);
    }

    float di = dinv[node];
    float* o = hws + (size_t)node * 32;
#pragma unroll 4
    for (int j = 0; j < 32; j++) {
        float a = 0.f;
#pragma unroll
        for (int k = 0; k < 32; k++) a += h[k] * sWg1[k * 32 + j];
        o[j] = a * di;
    }
}

// ---------------- bucketed gather: acc[dst] = sum hws[src] via LDS ----------------
__global__ __launch_bounds__(256) void gather_kernel(const unsigned int* __restrict__ bcount,
                                                     const unsigned int* __restrict__ packed,
                                                     const float* __restrict__ hws,
                                                     float* __restrict__ acc) {
    __shared__ float lacc[NPB * 32];  // 16 KB
    int b = blockIdx.x;
    for (int i = threadIdx.x; i < NPB * 32; i += 256) lacc[i] = 0.f;
    __syncthreads();
    unsigned int n = bcount[b];
    const unsigned int* pk = packed + (size_t)b * CAP;
    int g = threadIdx.x >> 5;  // edge group 0..7
    int f = threadIdx.x & 31;  // feature
    for (unsigned int i = g * 4; i < n; i += 32) {
#pragma unroll
        for (int u = 0; u < 4; u++) {
            unsigned int idx = i + u;
            if (idx < n) {
                unsigned int p = pk[idx];
                unsigned int s = p & 0x1FFFFu;
                unsigned int dl = p >> 17;
                float v = hws[(size_t)s * 32 + f];
                atomicAdd(&lacc[dl * 32 + f], v);  // ds_add_f32, 2-way alias = free
            }
        }
    }
    __syncthreads();
    int base = b * NPB;
    for (int i = threadIdx.x; i < NPB * 32; i += 256) {
        int node = base + (i >> 5);
        if (node < NN) acc[(size_t)node * 32 + (i & 31)] = lacc[i];
    }
}

// ---------------- conv1 epilogue + hw2 = (relu(...) @ Wg2) * dinv ----------------
__global__ __launch_bounds__(256) void finish1_kernel(
    const float* __restrict__ bg1, const float* __restrict__ Wg2,
    const float* __restrict__ dinv, float* __restrict__ hws, const float* __restrict__ acc) {
    __shared__ float sW[32 * 32];
    __shared__ float sb[32];
    for (int i = threadIdx.x; i < 32 * 32; i += 256) sW[i] = Wg2[i];
    if (threadIdx.x < 32) sb[threadIdx.x] = bg1[threadIdx.x];
    __syncthreads();

    int node = blockIdx.x * 256 + threadIdx.x;
    if (node >= NN) return;
    float di = dinv[node];
    float* hp = hws + (size_t)node * 32;
    const float* ap = acc + (size_t)node * 32;
    float h[32];
#pragma unroll
    for (int j = 0; j < 32; j++) {
        float v = di * (ap[j] + hp[j]) + sb[j];
        h[j] = v > 0.f ? v : 0.f;
    }
#pragma unroll 4
    for (int j = 0; j < 32; j++) {
        float a = 0.f;
#pragma unroll
        for (int k = 0; k < 32; k++) a += h[k] * sW[k * 32 + j];
        hp[j] = a * di;
    }
}

// ---------------- conv2 epilogue + prediction MLP ----------------
__global__ __launch_bounds__(256) void final_kernel(
    const float* __restrict__ bg2, const float* __restrict__ Wp1, const float* __restrict__ bp1,
    const float* __restrict__ Wp2, const float* __restrict__ bp2, const float* __restrict__ dinv,
    const float* __restrict__ hws, const float* __restrict__ acc, float* __restrict__ out) {
    __shared__ float sW1[32 * 32];
    __shared__ float sbg2[32];
    __shared__ float sb1[32];
    __shared__ float sW2[32];
    __shared__ float sb2;
    for (int i = threadIdx.x; i < 32 * 32; i += 256) sW1[i] = Wp1[i];
    if (threadIdx.x < 32) {
        sbg2[threadIdx.x] = bg2[threadIdx.x];
        sb1[threadIdx.x] = bp1[threadIdx.x];
        sW2[threadIdx.x] = Wp2[threadIdx.x];
    }
    if (threadIdx.x == 0) sb2 = bp2[0];
    __syncthreads();

    int node = blockIdx.x * 256 + threadIdx.x;
    if (node >= NN) return;
    float di = dinv[node];
    const float* hp = hws + (size_t)node * 32;
    const float* ap = acc + (size_t)node * 32;
    float h[32];
#pragma unroll
    for (int j = 0; j < 32; j++) {
        float v = di * (ap[j] + hp[j]) + sbg2[j];
        h[j] = v > 0.f ? v : 0.f;
    }
    float o = sb2;
#pragma unroll 4
    for (int j = 0; j < 32; j++) {
        float a = sb1[j];
#pragma unroll
        for (int k = 0; k < 32; k++) a += h[k] * sW1[k * 32 + j];
        o += tanhf(a) * sW2[j];
    }
    out[node] = tanhf(o);
}

extern "C" void kernel_launch(void* const* d_in, const int* in_sizes, int n_in,
                              void* d_out, int out_size, void* d_ws, size_t ws_size,
                              hipStream_t stream) {
    const float* x = (const float*)d_in[0];
    const int* edge = (const int*)d_in[1];  // [2, NE] int32
    const int* src = edge;
    const int* dst = edge + NE;
    const float* We1 = (const float*)d_in[2];
    const float* be1 = (const float*)d_in[3];
    const float* We2 = (const float*)d_in[4];
    const float* be2 = (const float*)d_in[5];
    const float* Wg1 = (const float*)d_in[6];
    const float* bg1 = (const float*)d_in[7];
    const float* Wg2 = (const float*)d_in[8];
    const float* bg2 = (const float*)d_in[9];
    const float* Wp1 = (const float*)d_in[10];
    const float* bp1 = (const float*)d_in[11];
    const float* Wp2 = (const float*)d_in[12];
    const float* bp2 = (const float*)d_in[13];
    float* out = (float*)d_out;

    // workspace (4B units):
    // bcount[1024] | dinv[NN] | hws[32NN] | acc[32NN] | packed[NBUCK*CAP]
    unsigned int* bcount = (unsigned int*)d_ws;
    float* dinv = (float*)d_ws + 1024;
    float* hws = (float*)d_ws + 1024 + NN;
    float* acc = (float*)d_ws + 1024 + NN + 32 * NN;
    unsigned int* packed = (unsigned int*)d_ws + 1024 + NN + 64 * NN;

    hipMemsetAsync(bcount, 0, 1024 * sizeof(unsigned int), stream);

    int gridN = (NN + 255) / 256;

    part_kernel<<<PBLOCKS, 256, 0, stream>>>(src, dst, bcount, packed);
    degdinv_kernel<<<NBUCK, 256, 0, stream>>>(bcount, packed, dinv);
    embed_kernel<<<gridN, 256, 0, stream>>>(x, We1, be1, We2, be2, Wg1, dinv, hws);
    gather_kernel<<<NBUCK, 256, 0, stream>>>(bcount, packed, hws, acc);
    finish1_kernel<<<gridN, 256, 0, stream>>>(bg1, Wg2, dinv, hws, acc);
    gather_kernel<<<NBUCK, 256, 0, stream>>>(bcount, packed, hws, acc);
    final_kernel<<<gridN, 256, 0, stream>>>(bg2, Wp1, bp1, Wp2, bp2, dinv, hws, acc, out);
}

// Round 4
// 389.082 us; speedup vs baseline: 2.3407x; 2.3407x over previous
//
#include <hip/hip_runtime.h>

#define NN 100000
#define NE 1600000
#define NPB 128                        // nodes per bucket
#define NBUCK ((NN + NPB - 1) / NPB)   // 782
#define CAP 2560                       // max edges/bucket (mean 2048, +11 sigma)
#define PBLOCKS 128
#define EPB (NE / PBLOCKS)             // 12500

// ---------------- bucket partition: packed[b*CAP + i] = (dst&127)<<17 | src ----------------
__global__ __launch_bounds__(256) void part_kernel(const int* __restrict__ src,
                                                   const int* __restrict__ dst,
                                                   unsigned int* __restrict__ bcount,
                                                   unsigned int* __restrict__ packed) {
    __shared__ unsigned int lcnt[NBUCK];
    __shared__ unsigned int lcur[NBUCK];
    for (int i = threadIdx.x; i < NBUCK; i += 256) lcnt[i] = 0u;
    __syncthreads();
    int e0 = blockIdx.x * EPB;
    for (int e = e0 + threadIdx.x; e < e0 + EPB; e += 256)
        atomicAdd(&lcnt[((unsigned)dst[e]) >> 7], 1u);
    __syncthreads();
    for (int i = threadIdx.x; i < NBUCK; i += 256) {
        unsigned int c = lcnt[i];
        lcur[i] = c ? atomicAdd(&bcount[i], c) : 0u;  // reserve contiguous run
    }
    __syncthreads();
    for (int e = e0 + threadIdx.x; e < e0 + EPB; e += 256) {
        unsigned int d = (unsigned)dst[e];
        unsigned int b = d >> 7;
        unsigned int pos = atomicAdd(&lcur[b], 1u);   // sequential within run
        packed[(size_t)b * CAP + pos] = ((d & 127u) << 17) | (unsigned)src[e];
    }
}

// ---------------- per-bucket counting sort (in place) + row_start/deg/dinv ----------------
__global__ __launch_bounds__(256) void sort_kernel(const unsigned int* __restrict__ bcount,
                                                   unsigned int* __restrict__ packed,
                                                   unsigned int* __restrict__ row_start,
                                                   unsigned int* __restrict__ degz,
                                                   float* __restrict__ dinv) {
    __shared__ unsigned int lraw[CAP];
    __shared__ unsigned int lsort[CAP];
    __shared__ unsigned int cnt[NPB];
    __shared__ unsigned int ps[NPB];
    __shared__ unsigned int cur[NPB];
    int b = blockIdx.x;
    int tid = threadIdx.x;
    if (tid < NPB) cnt[tid] = 0u;
    __syncthreads();
    unsigned int n = bcount[b];
    unsigned int* pk = packed + (size_t)b * CAP;
    for (unsigned int i = tid; i < n; i += 256) {
        unsigned int p = pk[i];
        lraw[i] = p;
        atomicAdd(&cnt[p >> 17], 1u);
    }
    __syncthreads();
    // Hillis-Steele inclusive prefix over 128
    if (tid < NPB) ps[tid] = cnt[tid];
    __syncthreads();
    for (int off = 1; off < NPB; off <<= 1) {
        unsigned int t = (tid < NPB && tid >= off) ? ps[tid - off] : 0u;
        __syncthreads();
        if (tid < NPB) ps[tid] += t;
        __syncthreads();
    }
    if (tid < NPB) cur[tid] = ps[tid] - cnt[tid];  // exclusive offsets
    __syncthreads();
    for (unsigned int i = tid; i < n; i += 256) {
        unsigned int p = lraw[i];
        unsigned int pos = atomicAdd(&cur[p >> 17], 1u);
        lsort[pos] = p & 0x1FFFFu;  // src only, sorted by local dst
    }
    __syncthreads();
    for (unsigned int i = tid; i < n; i += 256) pk[i] = lsort[i];
    if (tid < NPB) {
        int node = b * NPB + tid;
        if (node < NN) {
            unsigned int c = cnt[tid];
            row_start[node] = (unsigned int)(b * CAP) + ps[tid] - c;
            degz[node] = c;
            dinv[node] = rsqrtf((float)c + 1.0f);  // +1 self-loop
        }
    }
}

// ---------------- embed MLP + hw1 = (h @ Wg1) * dinv ----------------
__global__ __launch_bounds__(256) void embed_kernel(
    const float* __restrict__ x, const float* __restrict__ We1, const float* __restrict__ be1,
    const float* __restrict__ We2, const float* __restrict__ be2, const float* __restrict__ Wg1,
    const float* __restrict__ dinv, float* __restrict__ hws) {
    __shared__ float sWe1[6 * 64];
    __shared__ float sbe1[64];
    __shared__ float sWe2[64 * 32];
    __shared__ float sbe2[32];
    __shared__ float sWg1[32 * 32];
    for (int i = threadIdx.x; i < 6 * 64; i += 256) sWe1[i] = We1[i];
    for (int i = threadIdx.x; i < 64; i += 256) sbe1[i] = be1[i];
    for (int i = threadIdx.x; i < 64 * 32; i += 256) sWe2[i] = We2[i];
    for (int i = threadIdx.x; i < 32; i += 256) sbe2[i] = be2[i];
    for (int i = threadIdx.x; i < 32 * 32; i += 256) sWg1[i] = Wg1[i];
    __syncthreads();

    int node = blockIdx.x * 256 + threadIdx.x;
    if (node >= NN) return;

    float xv[6];
#pragma unroll
    for (int k = 0; k < 6; k++) xv[k] = x[node * 6 + k];

    float h1[64];
#pragma unroll
    for (int j = 0; j < 64; j++) {
        float a = sbe1[j];
#pragma unroll
        for (int k = 0; k < 6; k++) a += xv[k] * sWe1[k * 64 + j];
        h1[j] = tanhf(a);
    }

    float h[32];
#pragma unroll 4
    for (int j = 0; j < 32; j++) {
        float a = sbe2[j];
#pragma unroll
        for (int k = 0; k < 64; k++) a += h1[k] * sWe2[k * 32 + j];
        h[j] = tanhf(a);
    }

    float di = dinv[node];
    float* o = hws + (size_t)node * 32;
#pragma unroll 4
    for (int j = 0; j < 32; j++) {
        float a = 0.f;
#pragma unroll
        for (int k = 0; k < 32; k++) a += h[k] * sWg1[k * 32 + j];
        o[j] = a * di;
    }
}

// ---------------- gather: acc[n] = sum_{in-edges} hws[src] (wave per node) ----------------
__global__ __launch_bounds__(256) void gather_kernel(const unsigned int* __restrict__ sorted,
                                                     const unsigned int* __restrict__ row_start,
                                                     const unsigned int* __restrict__ degz,
                                                     const float* __restrict__ hws,
                                                     float* __restrict__ acc) {
    int wid = (blockIdx.x * 256 + threadIdx.x) >> 6;  // one wave per node
    if (wid >= NN) return;
    int lane = threadIdx.x & 63;
    int half = lane >> 5;
    int f = lane & 31;
    unsigned int base = row_start[wid];
    unsigned int d = degz[wid];
    float a = 0.f;
    for (unsigned int k = half; k < d; k += 2) {
        unsigned int s = sorted[base + k];
        a += hws[(size_t)s * 32 + f];
    }
    a += __shfl_down(a, 32);
    if (half == 0) acc[(size_t)wid * 32 + f] = a;
}

// ---------------- conv1 epilogue + hw2 = (relu(...) @ Wg2) * dinv ----------------
__global__ __launch_bounds__(256) void finish1_kernel(
    const float* __restrict__ bg1, const float* __restrict__ Wg2,
    const float* __restrict__ dinv, float* __restrict__ hws, const float* __restrict__ acc) {
    __shared__ float sW[32 * 32];
    __shared__ float sb[32];
    for (int i = threadIdx.x; i < 32 * 32; i += 256) sW[i] = Wg2[i];
    if (threadIdx.x < 32) sb[threadIdx.x] = bg1[threadIdx.x];
    __syncthreads();

    int node = blockIdx.x * 256 + threadIdx.x;
    if (node >= NN) return;
    float di = dinv[node];
    float* hp = hws + (size_t)node * 32;
    const float* ap = acc + (size_t)node * 32;
    float h[32];
#pragma unroll
    for (int j = 0; j < 32; j++) {
        float v = di * (ap[j] + hp[j]) + sb[j];
        h[j] = v > 0.f ? v : 0.f;
    }
#pragma unroll 4
    for (int j = 0; j < 32; j++) {
        float a = 0.f;
#pragma unroll
        for (int k = 0; k < 32; k++) a += h[k] * sW[k * 32 + j];
        hp[j] = a * di;
    }
}

// ---------------- conv2 epilogue + prediction MLP ----------------
__global__ __launch_bounds__(256) void final_kernel(
    const float* __restrict__ bg2, const float* __restrict__ Wp1, const float* __restrict__ bp1,
    const float* __restrict__ Wp2, const float* __restrict__ bp2, const float* __restrict__ dinv,
    const float* __restrict__ hws, const float* __restrict__ acc, float* __restrict__ out) {
    __shared__ float sW1[32 * 32];
    __shared__ float sbg2[32];
    __shared__ float sb1[32];
    __shared__ float sW2[32];
    __shared__ float sb2;
    for (int i = threadIdx.x; i < 32 * 32; i += 256) sW1[i] = Wp1[i];
    if (threadIdx.x < 32) {
        sbg2[threadIdx.x] = bg2[threadIdx.x];
        sb1[threadIdx.x] = bp1[threadIdx.x];
        sW2[threadIdx.x] = Wp2[threadIdx.x];
    }
    if (threadIdx.x == 0) sb2 = bp2[0];
    __syncthreads();

    int node = blockIdx.x * 256 + threadIdx.x;
    if (node >= NN) return;
    float di = dinv[node];
    const float* hp = hws + (size_t)node * 32;
    const float* ap = acc + (size_t)node * 32;
    float h[32];
#pragma unroll
    for (int j = 0; j < 32; j++) {
        float v = di * (ap[j] + hp[j]) + sbg2[j];
        h[j] = v > 0.f ? v : 0.f;
    }
    float o = sb2;
#pragma unroll 4
    for (int j = 0; j < 32; j++) {
        float a = sb1[j];
#pragma unroll
        for (int k = 0; k < 32; k++) a += h[k] * sW1[k * 32 + j];
        o += tanhf(a) * sW2[j];
    }
    out[node] = tanhf(o);
}

extern "C" void kernel_launch(void* const* d_in, const int* in_sizes, int n_in,
                              void* d_out, int out_size, void* d_ws, size_t ws_size,
                              hipStream_t stream) {
    const float* x = (const float*)d_in[0];
    const int* edge = (const int*)d_in[1];  // [2, NE] int32
    const int* src = edge;
    const int* dst = edge + NE;
    const float* We1 = (const float*)d_in[2];
    const float* be1 = (const float*)d_in[3];
    const float* We2 = (const float*)d_in[4];
    const float* be2 = (const float*)d_in[5];
    const float* Wg1 = (const float*)d_in[6];
    const float* bg1 = (const float*)d_in[7];
    const float* Wg2 = (const float*)d_in[8];
    const float* bg2 = (const float*)d_in[9];
    const float* Wp1 = (const float*)d_in[10];
    const float* bp1 = (const float*)d_in[11];
    const float* Wp2 = (const float*)d_in[12];
    const float* bp2 = (const float*)d_in[13];
    float* out = (float*)d_out;

    // workspace (4B units):
    // bcount[1024] | dinv[NN] | hws[32NN] | acc[32NN] | row_start[NN] | degz[NN] | packed[NBUCK*CAP]
    unsigned int* bcount = (unsigned int*)d_ws;
    float* dinv = (float*)d_ws + 1024;
    float* hws = (float*)d_ws + 1024 + NN;
    float* acc = (float*)d_ws + 1024 + NN + 32 * NN;
    unsigned int* row_start = (unsigned int*)d_ws + 1024 + 65 * NN;
    unsigned int* degz = (unsigned int*)d_ws + 1024 + 66 * NN;
    unsigned int* packed = (unsigned int*)d_ws + 1024 + 67 * NN;

    hipMemsetAsync(bcount, 0, 1024 * sizeof(unsigned int), stream);

    int gridN = (NN + 255) / 256;
    int gridG = (NN * 64 + 255) / 256;  // one wave per node

    part_kernel<<<PBLOCKS, 256, 0, stream>>>(src, dst, bcount, packed);
    sort_kernel<<<NBUCK, 256, 0, stream>>>(bcount, packed, row_start, degz, dinv);
    embed_kernel<<<gridN, 256, 0, stream>>>(x, We1, be1, We2, be2, Wg1, dinv, hws);
    gather_kernel<<<gridG, 256, 0, stream>>>(packed, row_start, degz, hws, acc);
    finish1_kernel<<<gridN, 256, 0, stream>>>(bg1, Wg2, dinv, hws, acc);
    gather_kernel<<<gridG, 256, 0, stream>>>(packed, row_start, degz, hws, acc);
    final_kernel<<<gridN, 256, 0, stream>>>(bg2, Wp1, bp1, Wp2, bp2, dinv, hws, acc, out);
}

// Round 5
// 375.289 us; speedup vs baseline: 2.4268x; 1.0368x over previous
//
#include <hip/hip_runtime.h>
#include <hip/hip_fp16.h>

#define NN 100000
#define NE 1600000
#define NPB 128                        // nodes per bucket
#define NBUCK ((NN + NPB - 1) / NPB)   // 782
#define CAP 2560                       // max edges/bucket (mean 2048, +11 sigma)
#define PBLOCKS 256
#define PTPB 1024
#define EPB (NE / PBLOCKS)             // 6250

// ---------------- bucket partition: packed[b*CAP + i] = (dst&127)<<17 | src ----------------
__global__ __launch_bounds__(PTPB) void part_kernel(const int* __restrict__ src,
                                                    const int* __restrict__ dst,
                                                    unsigned int* __restrict__ bcount,
                                                    unsigned int* __restrict__ packed) {
    __shared__ unsigned int lcnt[NBUCK];
    __shared__ unsigned int lcur[NBUCK];
    for (int i = threadIdx.x; i < NBUCK; i += PTPB) lcnt[i] = 0u;
    __syncthreads();
    int e0 = blockIdx.x * EPB;
    for (int e = e0 + threadIdx.x; e < e0 + EPB; e += PTPB)
        atomicAdd(&lcnt[((unsigned)dst[e]) >> 7], 1u);
    __syncthreads();
    for (int i = threadIdx.x; i < NBUCK; i += PTPB) {
        unsigned int c = lcnt[i];
        lcur[i] = c ? atomicAdd(&bcount[i], c) : 0u;  // reserve contiguous run
    }
    __syncthreads();
    for (int e = e0 + threadIdx.x; e < e0 + EPB; e += PTPB) {
        unsigned int d = (unsigned)dst[e];
        unsigned int b = d >> 7;
        unsigned int pos = atomicAdd(&lcur[b], 1u);   // sequential within run
        packed[(size_t)b * CAP + pos] = ((d & 127u) << 17) | (unsigned)src[e];
    }
}

// ---------------- per-bucket counting sort (in place) + row_start/deg/dinv ----------------
__global__ __launch_bounds__(256) void sort_kernel(const unsigned int* __restrict__ bcount,
                                                   unsigned int* __restrict__ packed,
                                                   unsigned int* __restrict__ row_start,
                                                   unsigned int* __restrict__ degz,
                                                   float* __restrict__ dinv) {
    __shared__ unsigned int lraw[CAP];
    __shared__ unsigned int lsort[CAP];
    __shared__ unsigned int cnt[NPB];
    __shared__ unsigned int ps[NPB];
    __shared__ unsigned int cur[NPB];
    int b = blockIdx.x;
    int tid = threadIdx.x;
    if (tid < NPB) cnt[tid] = 0u;
    __syncthreads();
    unsigned int n = bcount[b];
    unsigned int* pk = packed + (size_t)b * CAP;
    for (unsigned int i = tid; i < n; i += 256) {
        unsigned int p = pk[i];
        lraw[i] = p;
        atomicAdd(&cnt[p >> 17], 1u);
    }
    __syncthreads();
    if (tid < NPB) ps[tid] = cnt[tid];
    __syncthreads();
    for (int off = 1; off < NPB; off <<= 1) {
        unsigned int t = (tid < NPB && tid >= off) ? ps[tid - off] : 0u;
        __syncthreads();
        if (tid < NPB) ps[tid] += t;
        __syncthreads();
    }
    if (tid < NPB) cur[tid] = ps[tid] - cnt[tid];  // exclusive offsets
    __syncthreads();
    for (unsigned int i = tid; i < n; i += 256) {
        unsigned int p = lraw[i];
        unsigned int pos = atomicAdd(&cur[p >> 17], 1u);
        lsort[pos] = p & 0x1FFFFu;  // src only, sorted by local dst
    }
    __syncthreads();
    for (unsigned int i = tid; i < n; i += 256) pk[i] = lsort[i];
    if (tid < NPB) {
        int node = b * NPB + tid;
        if (node < NN) {
            unsigned int c = cnt[tid];
            row_start[node] = (unsigned int)(b * CAP) + ps[tid] - c;
            degz[node] = c;
            dinv[node] = rsqrtf((float)c + 1.0f);  // +1 self-loop
        }
    }
}

// ---------------- embed MLP + hws1 = fp16((h @ Wg1) * dinv) ----------------
__global__ __launch_bounds__(256) void embed_kernel(
    const float* __restrict__ x, const float* __restrict__ We1, const float* __restrict__ be1,
    const float* __restrict__ We2, const float* __restrict__ be2, const float* __restrict__ Wg1,
    const float* __restrict__ dinv, __half* __restrict__ hws1) {
    __shared__ float sWe1[6 * 64];
    __shared__ float sbe1[64];
    __shared__ float sWe2[64 * 32];
    __shared__ float sbe2[32];
    __shared__ float sWg1[32 * 32];
    for (int i = threadIdx.x; i < 6 * 64; i += 256) sWe1[i] = We1[i];
    for (int i = threadIdx.x; i < 64; i += 256) sbe1[i] = be1[i];
    for (int i = threadIdx.x; i < 64 * 32; i += 256) sWe2[i] = We2[i];
    for (int i = threadIdx.x; i < 32; i += 256) sbe2[i] = be2[i];
    for (int i = threadIdx.x; i < 32 * 32; i += 256) sWg1[i] = Wg1[i];
    __syncthreads();

    int node = blockIdx.x * 256 + threadIdx.x;
    if (node >= NN) return;

    float xv[6];
#pragma unroll
    for (int k = 0; k < 6; k++) xv[k] = x[node * 6 + k];

    float h1[64];
#pragma unroll
    for (int j = 0; j < 64; j++) {
        float a = sbe1[j];
#pragma unroll
        for (int k = 0; k < 6; k++) a += xv[k] * sWe1[k * 64 + j];
        h1[j] = tanhf(a);
    }

    float h[32];
#pragma unroll 4
    for (int j = 0; j < 32; j++) {
        float a = sbe2[j];
#pragma unroll
        for (int k = 0; k < 64; k++) a += h1[k] * sWe2[k * 32 + j];
        h[j] = tanhf(a);
    }

    float di = dinv[node];
    __half* o = hws1 + (size_t)node * 32;
#pragma unroll 4
    for (int j = 0; j < 32; j++) {
        float a = 0.f;
#pragma unroll
        for (int k = 0; k < 32; k++) a += h[k] * sWg1[k * 32 + j];
        o[j] = __float2half(a * di);
    }
}

// ---------------- gather1: conv1 + (relu @ Wg2)*dinv fused, wave per node ----------------
__global__ __launch_bounds__(256) void gather1_kernel(
    const unsigned int* __restrict__ sorted, const unsigned int* __restrict__ row_start,
    const unsigned int* __restrict__ degz, const float* __restrict__ dinv,
    const __half* __restrict__ hws1, const float* __restrict__ bg1,
    const float* __restrict__ Wg2, __half* __restrict__ hws2) {
    __shared__ float sW[32 * 32];
    __shared__ float sb[32];
    for (int i = threadIdx.x; i < 32 * 32; i += 256) sW[i] = Wg2[i];
    if (threadIdx.x < 32) sb[threadIdx.x] = bg1[threadIdx.x];
    __syncthreads();

    int wid = (blockIdx.x * 256 + threadIdx.x) >> 6;  // wave per node
    if (wid >= NN) return;
    int lane = threadIdx.x & 63;
    int half = lane >> 5;
    int f = lane & 31;
    unsigned int base = row_start[wid];
    unsigned int d = degz[wid];
    float a = 0.f;
    for (unsigned int k = half; k < d; k += 2) {
        unsigned int s = sorted[base + k];
        a += __half2float(hws1[(size_t)s * 32 + f]);
    }
    a += __shfl_xor(a, 32);                           // both halves: full sum
    a += __half2float(hws1[(size_t)wid * 32 + f]);    // self-loop term
    float di = dinv[wid];
    float h = di * a + sb[f];
    h = h > 0.f ? h : 0.f;
    float o = 0.f;
#pragma unroll 8
    for (int k = 0; k < 32; k++) {
        float hk = __shfl(h, k);                      // broadcast feature k
        o += hk * sW[k * 32 + f];
    }
    if (half == 0) hws2[(size_t)wid * 32 + f] = __float2half(o * di);
}

// ---------------- gather2: conv2 + prediction MLP fused, wave per node ----------------
__global__ __launch_bounds__(256) void gather2_kernel(
    const unsigned int* __restrict__ sorted, const unsigned int* __restrict__ row_start,
    const unsigned int* __restrict__ degz, const float* __restrict__ dinv,
    const __half* __restrict__ hws2, const float* __restrict__ bg2,
    const float* __restrict__ Wp1, const float* __restrict__ bp1,
    const float* __restrict__ Wp2, const float* __restrict__ bp2,
    float* __restrict__ out) {
    __shared__ float sW1[32 * 32];
    __shared__ float sbg2[32];
    __shared__ float sb1[32];
    __shared__ float sW2[32];
    __shared__ float sb2;
    for (int i = threadIdx.x; i < 32 * 32; i += 256) sW1[i] = Wp1[i];
    if (threadIdx.x < 32) {
        sbg2[threadIdx.x] = bg2[threadIdx.x];
        sb1[threadIdx.x] = bp1[threadIdx.x];
        sW2[threadIdx.x] = Wp2[threadIdx.x];
    }
    if (threadIdx.x == 0) sb2 = bp2[0];
    __syncthreads();

    int wid = (blockIdx.x * 256 + threadIdx.x) >> 6;  // wave per node
    if (wid >= NN) return;
    int lane = threadIdx.x & 63;
    int half = lane >> 5;
    int f = lane & 31;
    unsigned int base = row_start[wid];
    unsigned int d = degz[wid];
    float a = 0.f;
    for (unsigned int k = half; k < d; k += 2) {
        unsigned int s = sorted[base + k];
        a += __half2float(hws2[(size_t)s * 32 + f]);
    }
    a += __shfl_xor(a, 32);
    a += __half2float(hws2[(size_t)wid * 32 + f]);
    float di = dinv[wid];
    float h = di * a + sbg2[f];
    h = h > 0.f ? h : 0.f;
    float pre = sb1[f];
#pragma unroll 8
    for (int k = 0; k < 32; k++) {
        float hk = __shfl(h, k);
        pre += hk * sW1[k * 32 + f];
    }
    float t = tanhf(pre) * sW2[f];
#pragma unroll
    for (int off = 1; off < 32; off <<= 1) t += __shfl_xor(t, off);
    if (lane == 0) out[wid] = tanhf(t + sb2);
}

extern "C" void kernel_launch(void* const* d_in, const int* in_sizes, int n_in,
                              void* d_out, int out_size, void* d_ws, size_t ws_size,
                              hipStream_t stream) {
    const float* x = (const float*)d_in[0];
    const int* edge = (const int*)d_in[1];  // [2, NE] int32
    const int* src = edge;
    const int* dst = edge + NE;
    const float* We1 = (const float*)d_in[2];
    const float* be1 = (const float*)d_in[3];
    const float* We2 = (const float*)d_in[4];
    const float* be2 = (const float*)d_in[5];
    const float* Wg1 = (const float*)d_in[6];
    const float* bg1 = (const float*)d_in[7];
    const float* Wg2 = (const float*)d_in[8];
    const float* bg2 = (const float*)d_in[9];
    const float* Wp1 = (const float*)d_in[10];
    const float* bp1 = (const float*)d_in[11];
    const float* Wp2 = (const float*)d_in[12];
    const float* bp2 = (const float*)d_in[13];
    float* out = (float*)d_out;

    // workspace (4B units):
    // bcount[1024] | dinv[NN] | row_start[NN] | degz[NN] | packed[NBUCK*CAP] | hws1[16NN] | hws2[16NN]
    unsigned int* bcount = (unsigned int*)d_ws;
    float* dinv = (float*)d_ws + 1024;
    unsigned int* row_start = (unsigned int*)d_ws + 1024 + NN;
    unsigned int* degz = (unsigned int*)d_ws + 1024 + 2 * NN;
    unsigned int* packed = (unsigned int*)d_ws + 1024 + 3 * NN;
    __half* hws1 = (__half*)((unsigned int*)d_ws + 1024 + 3 * NN + NBUCK * CAP);
    __half* hws2 = (__half*)((unsigned int*)d_ws + 1024 + 3 * NN + NBUCK * CAP + 16 * NN);

    hipMemsetAsync(bcount, 0, 1024 * sizeof(unsigned int), stream);

    int gridN = (NN + 255) / 256;
    int gridG = (NN * 64 + 255) / 256;  // one wave per node

    part_kernel<<<PBLOCKS, PTPB, 0, stream>>>(src, dst, bcount, packed);
    sort_kernel<<<NBUCK, 256, 0, stream>>>(bcount, packed, row_start, degz, dinv);
    embed_kernel<<<gridN, 256, 0, stream>>>(x, We1, be1, We2, be2, Wg1, dinv, hws1);
    gather1_kernel<<<gridG, 256, 0, stream>>>(packed, row_start, degz, dinv, hws1, bg1, Wg2, hws2);
    gather2_kernel<<<gridG, 256, 0, stream>>>(packed, row_start, degz, dinv, hws2, bg2, Wp1, bp1, Wp2, bp2, out);
}

// Round 6
// 315.343 us; speedup vs baseline: 2.8881x; 1.1901x over previous
//
#include <hip/hip_runtime.h>
#include <hip/hip_fp16.h>

#define NN 100000
#define NE 1600000
#define NPB 128                        // nodes per bucket
#define NBUCK ((NN + NPB - 1) / NPB)   // 782
#define CAP 3584                       // max (padded) edges/bucket; mean 2048+448 pad
#define PBLOCKS 256
#define PTPB 1024
#define EPB (NE / PBLOCKS)             // 6250
#define DUMMY 100000u                  // sentinel src: hws row NN is all-zero

// ---------------- bucket partition: packed[b*CAP + i] = (dst&127)<<17 | src ----------------
__global__ __launch_bounds__(PTPB) void part_kernel(const int* __restrict__ src,
                                                    const int* __restrict__ dst,
                                                    unsigned int* __restrict__ bcount,
                                                    unsigned int* __restrict__ packed) {
    __shared__ unsigned int lcnt[NBUCK];
    __shared__ unsigned int lcur[NBUCK];
    for (int i = threadIdx.x; i < NBUCK; i += PTPB) lcnt[i] = 0u;
    __syncthreads();
    int e0 = blockIdx.x * EPB;
    for (int e = e0 + threadIdx.x; e < e0 + EPB; e += PTPB)
        atomicAdd(&lcnt[((unsigned)dst[e]) >> 7], 1u);
    __syncthreads();
    for (int i = threadIdx.x; i < NBUCK; i += PTPB) {
        unsigned int c = lcnt[i];
        lcur[i] = c ? atomicAdd(&bcount[i], c) : 0u;  // reserve contiguous run
    }
    __syncthreads();
    for (int e = e0 + threadIdx.x; e < e0 + EPB; e += PTPB) {
        unsigned int d = (unsigned)dst[e];
        unsigned int b = d >> 7;
        unsigned int pos = atomicAdd(&lcur[b], 1u);   // sequential within run
        packed[(size_t)b * CAP + pos] = ((d & 127u) << 17) | (unsigned)src[e];
    }
}

// ------- per-bucket counting sort (in place), pad each node list to mult of 8 -------
__global__ __launch_bounds__(256) void sort_kernel(const unsigned int* __restrict__ bcount,
                                                   unsigned int* __restrict__ packed,
                                                   unsigned int* __restrict__ row_start,
                                                   unsigned int* __restrict__ degz,
                                                   float* __restrict__ dinv) {
    __shared__ unsigned int lraw[CAP];
    __shared__ unsigned int lsort[CAP];
    __shared__ unsigned int cnt[NPB];
    __shared__ unsigned int ps[NPB];   // inclusive prefix of PADDED counts
    __shared__ unsigned int cur[NPB];
    __shared__ unsigned int ntot;
    int b = blockIdx.x;
    int tid = threadIdx.x;
    if (tid < NPB) cnt[tid] = 0u;
    __syncthreads();
    unsigned int n = bcount[b];
    unsigned int* pk = packed + (size_t)b * CAP;
    for (unsigned int i = tid; i < n; i += 256) {
        unsigned int p = pk[i];
        lraw[i] = p;
        atomicAdd(&cnt[p >> 17], 1u);
    }
    __syncthreads();
    if (tid < NPB) ps[tid] = (cnt[tid] + 7u) & ~7u;  // padded count
    __syncthreads();
    for (int off = 1; off < NPB; off <<= 1) {
        unsigned int t = (tid < NPB && tid >= off) ? ps[tid - off] : 0u;
        __syncthreads();
        if (tid < NPB) ps[tid] += t;
        __syncthreads();
    }
    if (tid == NPB - 1) ntot = ps[NPB - 1];
    __syncthreads();
    unsigned int np = ntot;
    for (unsigned int i = tid; i < np; i += 256) lsort[i] = DUMMY;
    if (tid < NPB) cur[tid] = ps[tid] - ((cnt[tid] + 7u) & ~7u);  // exclusive padded offset
    __syncthreads();
    for (unsigned int i = tid; i < n; i += 256) {
        unsigned int p = lraw[i];
        unsigned int pos = atomicAdd(&cur[p >> 17], 1u);
        lsort[pos] = p & 0x1FFFFu;  // src, sorted by local dst
    }
    __syncthreads();
    for (unsigned int i = tid; i < np; i += 256) pk[i] = lsort[i];
    if (tid < NPB) {
        int node = b * NPB + tid;
        if (node < NN) {
            unsigned int c = cnt[tid];
            unsigned int pc = (c + 7u) & ~7u;
            row_start[node] = (unsigned int)(b * CAP) + ps[tid] - pc;
            degz[node] = pc;                        // padded count (mult of 8)
            dinv[node] = rsqrtf((float)c + 1.0f);   // real deg + self-loop
        }
    }
}

// ---------------- embed MLP + hws1 = fp16((h @ Wg1) * dinv); zeros pad row NN ----------------
__global__ __launch_bounds__(256) void embed_kernel(
    const float* __restrict__ x, const float* __restrict__ We1, const float* __restrict__ be1,
    const float* __restrict__ We2, const float* __restrict__ be2, const float* __restrict__ Wg1,
    const float* __restrict__ dinv, __half* __restrict__ hws1, __half* __restrict__ hws2) {
    __shared__ float sWe1[6 * 64];
    __shared__ float sbe1[64];
    __shared__ float sWe2[64 * 32];
    __shared__ float sbe2[32];
    __shared__ float sWg1[32 * 32];
    for (int i = threadIdx.x; i < 6 * 64; i += 256) sWe1[i] = We1[i];
    for (int i = threadIdx.x; i < 64; i += 256) sbe1[i] = be1[i];
    for (int i = threadIdx.x; i < 64 * 32; i += 256) sWe2[i] = We2[i];
    for (int i = threadIdx.x; i < 32; i += 256) sbe2[i] = be2[i];
    for (int i = threadIdx.x; i < 32 * 32; i += 256) sWg1[i] = Wg1[i];
    __syncthreads();

    int node = blockIdx.x * 256 + threadIdx.x;
    if (node > NN) return;
    if (node == NN) {  // zero pad rows for DUMMY src
        for (int j = 0; j < 32; j++) {
            hws1[(size_t)NN * 32 + j] = __float2half(0.f);
            hws2[(size_t)NN * 32 + j] = __float2half(0.f);
        }
        return;
    }

    float xv[6];
#pragma unroll
    for (int k = 0; k < 6; k++) xv[k] = x[node * 6 + k];

    float h1[64];
#pragma unroll
    for (int j = 0; j < 64; j++) {
        float a = sbe1[j];
#pragma unroll
        for (int k = 0; k < 6; k++) a += xv[k] * sWe1[k * 64 + j];
        h1[j] = tanhf(a);
    }

    float h[32];
#pragma unroll 4
    for (int j = 0; j < 32; j++) {
        float a = sbe2[j];
#pragma unroll
        for (int k = 0; k < 64; k++) a += h1[k] * sWe2[k * 32 + j];
        h[j] = tanhf(a);
    }

    float di = dinv[node];
    __half* o = hws1 + (size_t)node * 32;
#pragma unroll 4
    for (int j = 0; j < 32; j++) {
        float a = 0.f;
#pragma unroll
        for (int k = 0; k < 32; k++) a += h[k] * sWg1[k * 32 + j];
        o[j] = __float2half(a * di);
    }
}

// ---------------- gather1: conv1 + (relu @ Wg2)*dinv fused, wave per node ----------------
__global__ __launch_bounds__(256) void gather1_kernel(
    const unsigned int* __restrict__ sorted, const unsigned int* __restrict__ row_start,
    const unsigned int* __restrict__ degz, const float* __restrict__ dinv,
    const __half* __restrict__ hws1, const float* __restrict__ bg1,
    const float* __restrict__ Wg2, __half* __restrict__ hws2) {
    __shared__ float sW[32 * 32];
    __shared__ float sb[32];
    for (int i = threadIdx.x; i < 32 * 32; i += 256) sW[i] = Wg2[i];
    if (threadIdx.x < 32) sb[threadIdx.x] = bg1[threadIdx.x];
    __syncthreads();

    int wid = (blockIdx.x * 256 + threadIdx.x) >> 6;  // wave per node
    if (wid >= NN) return;
    int lane = threadIdx.x & 63;
    int half = lane >> 5;
    int f = lane & 31;
    unsigned int base = row_start[wid];
    unsigned int d = degz[wid];  // multiple of 8
    float a = 0.f;
    for (unsigned int k = half; k < d; k += 8) {  // 4 edges per half per iter, no tail
        unsigned int s0 = sorted[base + k];
        unsigned int s1 = sorted[base + k + 2];
        unsigned int s2 = sorted[base + k + 4];
        unsigned int s3 = sorted[base + k + 6];
        float v0 = __half2float(hws1[(size_t)s0 * 32 + f]);
        float v1 = __half2float(hws1[(size_t)s1 * 32 + f]);
        float v2 = __half2float(hws1[(size_t)s2 * 32 + f]);
        float v3 = __half2float(hws1[(size_t)s3 * 32 + f]);
        a += (v0 + v1) + (v2 + v3);
    }
    a += __shfl_xor(a, 32);                           // full neighbor sum
    a += __half2float(hws1[(size_t)wid * 32 + f]);    // self-loop term
    float di = dinv[wid];
    float h = di * a + sb[f];
    h = h > 0.f ? h : 0.f;
    float o = 0.f;
#pragma unroll 8
    for (int k = 0; k < 32; k++) {
        float hk = __shfl(h, k);                      // broadcast feature k
        o += hk * sW[k * 32 + f];
    }
    if (half == 0) hws2[(size_t)wid * 32 + f] = __float2half(o * di);
}

// ---------------- gather2: conv2 + prediction MLP fused, wave per node ----------------
__global__ __launch_bounds__(256) void gather2_kernel(
    const unsigned int* __restrict__ sorted, const unsigned int* __restrict__ row_start,
    const unsigned int* __restrict__ degz, const float* __restrict__ dinv,
    const __half* __restrict__ hws2, const float* __restrict__ bg2,
    const float* __restrict__ Wp1, const float* __restrict__ bp1,
    const float* __restrict__ Wp2, const float* __restrict__ bp2,
    float* __restrict__ out) {
    __shared__ float sW1[32 * 32];
    __shared__ float sbg2[32];
    __shared__ float sb1[32];
    __shared__ float sW2[32];
    __shared__ float sb2;
    for (int i = threadIdx.x; i < 32 * 32; i += 256) sW1[i] = Wp1[i];
    if (threadIdx.x < 32) {
        sbg2[threadIdx.x] = bg2[threadIdx.x];
        sb1[threadIdx.x] = bp1[threadIdx.x];
        sW2[threadIdx.x] = Wp2[threadIdx.x];
    }
    if (threadIdx.x == 0) sb2 = bp2[0];
    __syncthreads();

    int wid = (blockIdx.x * 256 + threadIdx.x) >> 6;  // wave per node
    if (wid >= NN) return;
    int lane = threadIdx.x & 63;
    int half = lane >> 5;
    int f = lane & 31;
    unsigned int base = row_start[wid];
    unsigned int d = degz[wid];
    float a = 0.f;
    for (unsigned int k = half; k < d; k += 8) {
        unsigned int s0 = sorted[base + k];
        unsigned int s1 = sorted[base + k + 2];
        unsigned int s2 = sorted[base + k + 4];
        unsigned int s3 = sorted[base + k + 6];
        float v0 = __half2float(hws2[(size_t)s0 * 32 + f]);
        float v1 = __half2float(hws2[(size_t)s1 * 32 + f]);
        float v2 = __half2float(hws2[(size_t)s2 * 32 + f]);
        float v3 = __half2float(hws2[(size_t)s3 * 32 + f]);
        a += (v0 + v1) + (v2 + v3);
    }
    a += __shfl_xor(a, 32);
    a += __half2float(hws2[(size_t)wid * 32 + f]);
    float di = dinv[wid];
    float h = di * a + sbg2[f];
    h = h > 0.f ? h : 0.f;
    float pre = sb1[f];
#pragma unroll 8
    for (int k = 0; k < 32; k++) {
        float hk = __shfl(h, k);
        pre += hk * sW1[k * 32 + f];
    }
    float t = tanhf(pre) * sW2[f];
#pragma unroll
    for (int off = 1; off < 32; off <<= 1) t += __shfl_xor(t, off);
    if (lane == 0) out[wid] = tanhf(t + sb2);
}

extern "C" void kernel_launch(void* const* d_in, const int* in_sizes, int n_in,
                              void* d_out, int out_size, void* d_ws, size_t ws_size,
                              hipStream_t stream) {
    const float* x = (const float*)d_in[0];
    const int* edge = (const int*)d_in[1];  // [2, NE] int32
    const int* src = edge;
    const int* dst = edge + NE;
    const float* We1 = (const float*)d_in[2];
    const float* be1 = (const float*)d_in[3];
    const float* We2 = (const float*)d_in[4];
    const float* be2 = (const float*)d_in[5];
    const float* Wg1 = (const float*)d_in[6];
    const float* bg1 = (const float*)d_in[7];
    const float* Wg2 = (const float*)d_in[8];
    const float* bg2 = (const float*)d_in[9];
    const float* Wp1 = (const float*)d_in[10];
    const float* bp1 = (const float*)d_in[11];
    const float* Wp2 = (const float*)d_in[12];
    const float* bp2 = (const float*)d_in[13];
    float* out = (float*)d_out;

    // workspace (4B units):
    // bcount[1024] | dinv[NN] | row_start[NN] | degz[NN] | packed[NBUCK*CAP] | hws1 | hws2
    unsigned int* bcount = (unsigned int*)d_ws;
    float* dinv = (float*)d_ws + 1024;
    unsigned int* row_start = (unsigned int*)d_ws + 1024 + NN;
    unsigned int* degz = (unsigned int*)d_ws + 1024 + 2 * NN;
    unsigned int* packed = (unsigned int*)d_ws + 1024 + 3 * NN;
    // fp16 buffers, (NN+1) rows of 32 halfs each (row NN = zero pad row)
    __half* hws1 = (__half*)((unsigned int*)d_ws + 1024 + 3 * NN + NBUCK * CAP);
    __half* hws2 = hws1 + (size_t)(NN + 1) * 32;

    hipMemsetAsync(bcount, 0, 1024 * sizeof(unsigned int), stream);

    int gridN = (NN + 256) / 256;       // covers node NN (pad-row writer)
    int gridG = (NN * 64 + 255) / 256;  // one wave per node

    part_kernel<<<PBLOCKS, PTPB, 0, stream>>>(src, dst, bcount, packed);
    sort_kernel<<<NBUCK, 256, 0, stream>>>(bcount, packed, row_start, degz, dinv);
    embed_kernel<<<gridN, 256, 0, stream>>>(x, We1, be1, We2, be2, Wg1, dinv, hws1, hws2);
    gather1_kernel<<<gridG, 256, 0, stream>>>(packed, row_start, degz, dinv, hws1, bg1, Wg2, hws2);
    gather2_kernel<<<gridG, 256, 0, stream>>>(packed, row_start, degz, dinv, hws2, bg2, Wp1, bp1, Wp2, bp2, out);
}

// Round 7
// 307.157 us; speedup vs baseline: 2.9651x; 1.0267x over previous
//
#include <hip/hip_runtime.h>
#include <hip/hip_fp16.h>

#define NN 100000
#define NE 1600000
#define NPB 128                        // nodes per bucket
#define NBUCK ((NN + NPB - 1) / NPB)   // 782
#define CAP 4096                       // reserved slots per bucket (mean ~2950, +11 sigma)
#define PBLOCKS 128
#define PTPB 1024
#define EPB (NE / PBLOCKS)             // 12500
#define DUMMY 100000u                  // pad src: hws row NN is all-zero
#define SENT 0xFFFFFFFFu               // reservation-slack sentinel

// ---- bucket partition, 64B-aligned per-(block,bucket) runs: packed = (dst&127)<<17 | src ----
__global__ __launch_bounds__(PTPB) void part_kernel(const int* __restrict__ src,
                                                    const int* __restrict__ dst,
                                                    unsigned int* __restrict__ bcount,
                                                    unsigned int* __restrict__ packed) {
    __shared__ unsigned int lcnt[NBUCK];
    __shared__ unsigned int lcur[NBUCK];
    __shared__ unsigned int lend[NBUCK];
    for (int i = threadIdx.x; i < NBUCK; i += PTPB) lcnt[i] = 0u;
    __syncthreads();
    int e0 = blockIdx.x * EPB;
    for (int e = e0 + threadIdx.x; e < e0 + EPB; e += PTPB)
        atomicAdd(&lcnt[((unsigned)dst[e]) >> 7], 1u);
    __syncthreads();
    for (int i = threadIdx.x; i < NBUCK; i += PTPB) {
        unsigned int c = lcnt[i];
        unsigned int rc = (c + 15u) & ~15u;              // line-aligned reservation
        unsigned int base = rc ? atomicAdd(&bcount[i], rc) : 0u;
        lcur[i] = base;
        lend[i] = base + rc;
    }
    __syncthreads();
    for (int e = e0 + threadIdx.x; e < e0 + EPB; e += PTPB) {
        unsigned int d = (unsigned)dst[e];
        unsigned int b = d >> 7;
        unsigned int pos = atomicAdd(&lcur[b], 1u);
        packed[(size_t)b * CAP + pos] = ((d & 127u) << 17) | (unsigned)src[e];
    }
    __syncthreads();
    for (int i = threadIdx.x; i < NBUCK; i += PTPB)      // fill slack with sentinel
        for (unsigned int j = lcur[i]; j < lend[i]; j++)
            packed[(size_t)i * CAP + j] = SENT;
}

// ---- per-bucket counting sort (skip sentinels), pad each node list to mult of 16 ----
__global__ __launch_bounds__(256) void sort_kernel(const unsigned int* __restrict__ bcount,
                                                   unsigned int* __restrict__ packed,
                                                   unsigned int* __restrict__ row_start,
                                                   unsigned int* __restrict__ degz,
                                                   float* __restrict__ dinv) {
    __shared__ unsigned int lraw[CAP];
    __shared__ unsigned int lsort[CAP];
    __shared__ unsigned int cnt[NPB];
    __shared__ unsigned int ps[NPB];   // inclusive prefix of PADDED counts
    __shared__ unsigned int cur[NPB];
    __shared__ unsigned int ntot;
    int b = blockIdx.x;
    int tid = threadIdx.x;
    if (tid < NPB) cnt[tid] = 0u;
    __syncthreads();
    unsigned int n = bcount[b];        // reserved total (includes sentinel holes)
    unsigned int* pk = packed + (size_t)b * CAP;
    for (unsigned int i = tid; i < n; i += 256) {
        unsigned int p = pk[i];
        lraw[i] = p;
        if (p != SENT) atomicAdd(&cnt[p >> 17], 1u);
    }
    __syncthreads();
    if (tid < NPB) ps[tid] = (cnt[tid] + 15u) & ~15u;  // padded count
    __syncthreads();
    for (int off = 1; off < NPB; off <<= 1) {
        unsigned int t = (tid < NPB && tid >= off) ? ps[tid - off] : 0u;
        __syncthreads();
        if (tid < NPB) ps[tid] += t;
        __syncthreads();
    }
    if (tid == NPB - 1) ntot = ps[NPB - 1];
    __syncthreads();
    unsigned int np = ntot;
    for (unsigned int i = tid; i < np; i += 256) lsort[i] = DUMMY;
    if (tid < NPB) cur[tid] = ps[tid] - ((cnt[tid] + 15u) & ~15u);
    __syncthreads();
    for (unsigned int i = tid; i < n; i += 256) {
        unsigned int p = lraw[i];
        if (p != SENT) {
            unsigned int pos = atomicAdd(&cur[p >> 17], 1u);
            lsort[pos] = p & 0x1FFFFu;
        }
    }
    __syncthreads();
    for (unsigned int i = tid; i < np; i += 256) pk[i] = lsort[i];
    if (tid < NPB) {
        int node = b * NPB + tid;
        if (node < NN) {
            unsigned int c = cnt[tid];
            unsigned int pc = (c + 15u) & ~15u;
            row_start[node] = (unsigned int)(b * CAP) + ps[tid] - pc;
            degz[node] = pc;                        // padded count (mult of 16)
            dinv[node] = rsqrtf((float)c + 1.0f);   // real deg + self-loop
        }
    }
}

// ---------------- embed MLP + hws1 = fp16((h @ Wg1) * dinv); zeros pad row NN ----------------
__global__ __launch_bounds__(256) void embed_kernel(
    const float* __restrict__ x, const float* __restrict__ We1, const float* __restrict__ be1,
    const float* __restrict__ We2, const float* __restrict__ be2, const float* __restrict__ Wg1,
    const float* __restrict__ dinv, __half* __restrict__ hws1, __half* __restrict__ hws2) {
    __shared__ float sWe1[6 * 64];
    __shared__ float sbe1[64];
    __shared__ float sWe2[64 * 32];
    __shared__ float sbe2[32];
    __shared__ float sWg1[32 * 32];
    for (int i = threadIdx.x; i < 6 * 64; i += 256) sWe1[i] = We1[i];
    for (int i = threadIdx.x; i < 64; i += 256) sbe1[i] = be1[i];
    for (int i = threadIdx.x; i < 64 * 32; i += 256) sWe2[i] = We2[i];
    for (int i = threadIdx.x; i < 32; i += 256) sbe2[i] = be2[i];
    for (int i = threadIdx.x; i < 32 * 32; i += 256) sWg1[i] = Wg1[i];
    __syncthreads();

    int node = blockIdx.x * 256 + threadIdx.x;
    if (node > NN) return;
    if (node == NN) {  // zero pad rows for DUMMY src
        for (int j = 0; j < 32; j++) {
            hws1[(size_t)NN * 32 + j] = __float2half(0.f);
            hws2[(size_t)NN * 32 + j] = __float2half(0.f);
        }
        return;
    }

    float xv[6];
#pragma unroll
    for (int k = 0; k < 6; k++) xv[k] = x[node * 6 + k];

    float h1[64];
#pragma unroll
    for (int j = 0; j < 64; j++) {
        float a = sbe1[j];
#pragma unroll
        for (int k = 0; k < 6; k++) a += xv[k] * sWe1[k * 64 + j];
        h1[j] = tanhf(a);
    }

    float h[32];
#pragma unroll 4
    for (int j = 0; j < 32; j++) {
        float a = sbe2[j];
#pragma unroll
        for (int k = 0; k < 64; k++) a += h1[k] * sWe2[k * 32 + j];
        h[j] = tanhf(a);
    }

    float di = dinv[node];
    __half* o = hws1 + (size_t)node * 32;
#pragma unroll 4
    for (int j = 0; j < 32; j++) {
        float a = 0.f;
#pragma unroll
        for (int k = 0; k < 32; k++) a += h[k] * sWg1[k * 32 + j];
        o[j] = __float2half(a * di);
    }
}

// ---- gather1: conv1 + (relu @ Wg2)*dinv fused; 4 groups x 16 lanes, half2 loads ----
__global__ __launch_bounds__(256) void gather1_kernel(
    const unsigned int* __restrict__ sorted, const unsigned int* __restrict__ row_start,
    const unsigned int* __restrict__ degz, const float* __restrict__ dinv,
    const __half* __restrict__ hws1, const float* __restrict__ bg1,
    const float* __restrict__ Wg2, __half* __restrict__ hws2) {
    __shared__ float sW[32 * 32];
    __shared__ float sb[32];
    for (int i = threadIdx.x; i < 32 * 32; i += 256) sW[i] = Wg2[i];
    if (threadIdx.x < 32) sb[threadIdx.x] = bg1[threadIdx.x];
    __syncthreads();

    int wid = (blockIdx.x * 256 + threadIdx.x) >> 6;  // wave per node
    if (wid >= NN) return;
    int lane = threadIdx.x & 63;
    int g = lane >> 4;   // edge group 0..3
    int p = lane & 15;   // feature pair
    unsigned int base = row_start[wid];
    unsigned int d = degz[wid];  // multiple of 16
    const __half2* H = (const __half2*)hws1;
    float ax = 0.f, ay = 0.f;
    for (unsigned int k = g; k < d; k += 16) {  // 16 rows in flight per wave
        unsigned int s0 = sorted[base + k];
        unsigned int s1 = sorted[base + k + 4];
        unsigned int s2 = sorted[base + k + 8];
        unsigned int s3 = sorted[base + k + 12];
        float2 v0 = __half22float2(H[(size_t)s0 * 16 + p]);
        float2 v1 = __half22float2(H[(size_t)s1 * 16 + p]);
        float2 v2 = __half22float2(H[(size_t)s2 * 16 + p]);
        float2 v3 = __half22float2(H[(size_t)s3 * 16 + p]);
        ax += (v0.x + v1.x) + (v2.x + v3.x);
        ay += (v0.y + v1.y) + (v2.y + v3.y);
    }
    ax += __shfl_xor(ax, 16); ay += __shfl_xor(ay, 16);
    ax += __shfl_xor(ax, 32); ay += __shfl_xor(ay, 32);
    float2 sv = __half22float2(H[(size_t)wid * 16 + p]);  // self-loop term
    ax += sv.x; ay += sv.y;
    float di = dinv[wid];
    float hx = di * ax + sb[2 * p];     hx = hx > 0.f ? hx : 0.f;
    float hy = di * ay + sb[2 * p + 1]; hy = hy > 0.f ? hy : 0.f;
    int f = lane & 31;                  // redistribute: one feature per lane
    float hxe = __shfl(hx, f >> 1);
    float hye = __shfl(hy, f >> 1);
    float h = (f & 1) ? hye : hxe;
    float o = 0.f;
#pragma unroll 8
    for (int k = 0; k < 32; k++) {
        float hk = __shfl(h, k);
        o += hk * sW[k * 32 + f];
    }
    if (lane < 32) hws2[(size_t)wid * 32 + f] = __float2half(o * di);
}

// ---- gather2: conv2 + prediction MLP fused; same structure ----
__global__ __launch_bounds__(256) void gather2_kernel(
    const unsigned int* __restrict__ sorted, const unsigned int* __restrict__ row_start,
    const unsigned int* __restrict__ degz, const float* __restrict__ dinv,
    const __half* __restrict__ hws2, const float* __restrict__ bg2,
    const float* __restrict__ Wp1, const float* __restrict__ bp1,
    const float* __restrict__ Wp2, const float* __restrict__ bp2,
    float* __restrict__ out) {
    __shared__ float sW1[32 * 32];
    __shared__ float sbg2[32];
    __shared__ float sb1[32];
    __shared__ float sW2[32];
    __shared__ float sb2;
    for (int i = threadIdx.x; i < 32 * 32; i += 256) sW1[i] = Wp1[i];
    if (threadIdx.x < 32) {
        sbg2[threadIdx.x] = bg2[threadIdx.x];
        sb1[threadIdx.x] = bp1[threadIdx.x];
        sW2[threadIdx.x] = Wp2[threadIdx.x];
    }
    if (threadIdx.x == 0) sb2 = bp2[0];
    __syncthreads();

    int wid = (blockIdx.x * 256 + threadIdx.x) >> 6;
    if (wid >= NN) return;
    int lane = threadIdx.x & 63;
    int g = lane >> 4;
    int p = lane & 15;
    unsigned int base = row_start[wid];
    unsigned int d = degz[wid];
    const __half2* H = (const __half2*)hws2;
    float ax = 0.f, ay = 0.f;
    for (unsigned int k = g; k < d; k += 16) {
        unsigned int s0 = sorted[base + k];
        unsigned int s1 = sorted[base + k + 4];
        unsigned int s2 = sorted[base + k + 8];
        unsigned int s3 = sorted[base + k + 12];
        float2 v0 = __half22float2(H[(size_t)s0 * 16 + p]);
        float2 v1 = __half22float2(H[(size_t)s1 * 16 + p]);
        float2 v2 = __half22float2(H[(size_t)s2 * 16 + p]);
        float2 v3 = __half22float2(H[(size_t)s3 * 16 + p]);
        ax += (v0.x + v1.x) + (v2.x + v3.x);
        ay += (v0.y + v1.y) + (v2.y + v3.y);
    }
    ax += __shfl_xor(ax, 16); ay += __shfl_xor(ay, 16);
    ax += __shfl_xor(ax, 32); ay += __shfl_xor(ay, 32);
    float2 sv = __half22float2(H[(size_t)wid * 16 + p]);
    ax += sv.x; ay += sv.y;
    float di = dinv[wid];
    float hx = di * ax + sbg2[2 * p];     hx = hx > 0.f ? hx : 0.f;
    float hy = di * ay + sbg2[2 * p + 1]; hy = hy > 0.f ? hy : 0.f;
    int f = lane & 31;
    float hxe = __shfl(hx, f >> 1);
    float hye = __shfl(hy, f >> 1);
    float h = (f & 1) ? hye : hxe;
    float pre = sb1[f];
#pragma unroll 8
    for (int k = 0; k < 32; k++) {
        float hk = __shfl(h, k);
        pre += hk * sW1[k * 32 + f];
    }
    float t = tanhf(pre) * sW2[f];
#pragma unroll
    for (int off = 1; off < 32; off <<= 1) t += __shfl_xor(t, off);
    if (lane == 0) out[wid] = tanhf(t + sb2);
}

extern "C" void kernel_launch(void* const* d_in, const int* in_sizes, int n_in,
                              void* d_out, int out_size, void* d_ws, size_t ws_size,
                              hipStream_t stream) {
    const float* x = (const float*)d_in[0];
    const int* edge = (const int*)d_in[1];  // [2, NE] int32
    const int* src = edge;
    const int* dst = edge + NE;
    const float* We1 = (const float*)d_in[2];
    const float* be1 = (const float*)d_in[3];
    const float* We2 = (const float*)d_in[4];
    const float* be2 = (const float*)d_in[5];
    const float* Wg1 = (const float*)d_in[6];
    const float* bg1 = (const float*)d_in[7];
    const float* Wg2 = (const float*)d_in[8];
    const float* bg2 = (const float*)d_in[9];
    const float* Wp1 = (const float*)d_in[10];
    const float* bp1 = (const float*)d_in[11];
    const float* Wp2 = (const float*)d_in[12];
    const float* bp2 = (const float*)d_in[13];
    float* out = (float*)d_out;

    // workspace (4B units):
    // bcount[1024] | dinv[NN] | row_start[NN] | degz[NN] | packed[NBUCK*CAP] | hws1 | hws2
    unsigned int* bcount = (unsigned int*)d_ws;
    float* dinv = (float*)d_ws + 1024;
    unsigned int* row_start = (unsigned int*)d_ws + 1024 + NN;
    unsigned int* degz = (unsigned int*)d_ws + 1024 + 2 * NN;
    unsigned int* packed = (unsigned int*)d_ws + 1024 + 3 * NN;
    // fp16 buffers, (NN+1) rows of 32 halfs each (row NN = zero pad row)
    __half* hws1 = (__half*)((unsigned int*)d_ws + 1024 + 3 * NN + NBUCK * CAP);
    __half* hws2 = hws1 + (size_t)(NN + 1) * 32;

    hipMemsetAsync(bcount, 0, 1024 * sizeof(unsigned int), stream);

    int gridN = (NN + 256) / 256;       // covers node NN (pad-row writer)
    int gridG = (NN * 64 + 255) / 256;  // one wave per node

    part_kernel<<<PBLOCKS, PTPB, 0, stream>>>(src, dst, bcount, packed);
    sort_kernel<<<NBUCK, 256, 0, stream>>>(bcount, packed, row_start, degz, dinv);
    embed_kernel<<<gridN, 256, 0, stream>>>(x, We1, be1, We2, be2, Wg1, dinv, hws1, hws2);
    gather1_kernel<<<gridG, 256, 0, stream>>>(packed, row_start, degz, dinv, hws1, bg1, Wg2, hws2);
    gather2_kernel<<<gridG, 256, 0, stream>>>(packed, row_start, degz, dinv, hws2, bg2, Wp1, bp1, Wp2, bp2, out);
}

// Round 8
// 278.914 us; speedup vs baseline: 3.2653x; 1.1013x over previous
//
#include <hip/hip_runtime.h>
#include <hip/hip_fp16.h>

#define NN 100000
#define NE 1600000
#define NPB 128                        // nodes per bucket
#define NBUCK ((NN + NPB - 1) / NPB)   // 782
#define CAP 4096                       // reserved slots per bucket
#define PBLOCKS 128
#define PTPB 1024
#define EPB (NE / PBLOCKS)             // 12500
#define DUMMY 100000u                  // pad src: hws row NN is all-zero
#define SENT 0xFFFFFFFFu               // reservation-slack sentinel
#define GBLK 2048                      // gather blocks
#define GWAVES (GBLK * 4)              // 8192 persistent waves

// ---- bucket partition, 64B-aligned per-(block,bucket) runs: packed = (dst&127)<<17 | src ----
__global__ __launch_bounds__(PTPB) void part_kernel(const int* __restrict__ src,
                                                    const int* __restrict__ dst,
                                                    unsigned int* __restrict__ bcount,
                                                    unsigned int* __restrict__ packed) {
    __shared__ unsigned int lcnt[NBUCK];
    __shared__ unsigned int lcur[NBUCK];
    __shared__ unsigned int lend[NBUCK];
    for (int i = threadIdx.x; i < NBUCK; i += PTPB) lcnt[i] = 0u;
    __syncthreads();
    int e0 = blockIdx.x * EPB;
    for (int e = e0 + threadIdx.x; e < e0 + EPB; e += PTPB)
        atomicAdd(&lcnt[((unsigned)dst[e]) >> 7], 1u);
    __syncthreads();
    for (int i = threadIdx.x; i < NBUCK; i += PTPB) {
        unsigned int c = lcnt[i];
        unsigned int rc = (c + 15u) & ~15u;              // line-aligned reservation
        unsigned int base = rc ? atomicAdd(&bcount[i], rc) : 0u;
        lcur[i] = base;
        lend[i] = base + rc;
    }
    __syncthreads();
    for (int e = e0 + threadIdx.x; e < e0 + EPB; e += PTPB) {
        unsigned int d = (unsigned)dst[e];
        unsigned int b = d >> 7;
        unsigned int pos = atomicAdd(&lcur[b], 1u);
        packed[(size_t)b * CAP + pos] = ((d & 127u) << 17) | (unsigned)src[e];
    }
    __syncthreads();
    for (int i = threadIdx.x; i < NBUCK; i += PTPB)      // fill slack with sentinel
        for (unsigned int j = lcur[i]; j < lend[i]; j++)
            packed[(size_t)i * CAP + j] = SENT;
}

// ---- per-bucket counting sort (skip sentinels), pad node lists to mult of 16 ----
// writes rsd[node] = row_start | (padded_deg/16)<<22  and dinv[node]
__global__ __launch_bounds__(256) void sort_kernel(const unsigned int* __restrict__ bcount,
                                                   unsigned int* __restrict__ packed,
                                                   unsigned int* __restrict__ rsd,
                                                   float* __restrict__ dinv) {
    __shared__ unsigned int lraw[CAP];
    __shared__ unsigned int lsort[CAP];
    __shared__ unsigned int cnt[NPB];
    __shared__ unsigned int ps[NPB];   // inclusive prefix of PADDED counts
    __shared__ unsigned int cur[NPB];
    __shared__ unsigned int ntot;
    int b = blockIdx.x;
    int tid = threadIdx.x;
    if (tid < NPB) cnt[tid] = 0u;
    __syncthreads();
    unsigned int n = bcount[b];        // reserved total (includes sentinel holes)
    unsigned int* pk = packed + (size_t)b * CAP;
    for (unsigned int i = tid; i < n; i += 256) {
        unsigned int p = pk[i];
        lraw[i] = p;
        if (p != SENT) atomicAdd(&cnt[p >> 17], 1u);
    }
    __syncthreads();
    if (tid < NPB) ps[tid] = (cnt[tid] + 15u) & ~15u;  // padded count
    __syncthreads();
    for (int off = 1; off < NPB; off <<= 1) {
        unsigned int t = (tid < NPB && tid >= off) ? ps[tid - off] : 0u;
        __syncthreads();
        if (tid < NPB) ps[tid] += t;
        __syncthreads();
    }
    if (tid == NPB - 1) ntot = ps[NPB - 1];
    __syncthreads();
    unsigned int np = ntot;
    for (unsigned int i = tid; i < np; i += 256) lsort[i] = DUMMY;
    if (tid < NPB) cur[tid] = ps[tid] - ((cnt[tid] + 15u) & ~15u);
    __syncthreads();
    for (unsigned int i = tid; i < n; i += 256) {
        unsigned int p = lraw[i];
        if (p != SENT) {
            unsigned int pos = atomicAdd(&cur[p >> 17], 1u);
            lsort[pos] = p & 0x1FFFFu;
        }
    }
    __syncthreads();
    for (unsigned int i = tid; i < np; i += 256) pk[i] = lsort[i];
    if (tid < NPB) {
        int node = b * NPB + tid;
        if (node < NN) {
            unsigned int c = cnt[tid];
            unsigned int pc = (c + 15u) & ~15u;
            unsigned int rs = (unsigned int)(b * CAP) + ps[tid] - pc;  // < 2^22
            rsd[node] = rs | ((pc >> 4) << 22);
            dinv[node] = rsqrtf((float)c + 1.0f);   // real deg + self-loop
        }
    }
}

// ---------------- embed MLP + hws1 = fp16((h @ Wg1) * dinv); zeros pad row NN ----------------
__global__ __launch_bounds__(256) void embed_kernel(
    const float* __restrict__ x, const float* __restrict__ We1, const float* __restrict__ be1,
    const float* __restrict__ We2, const float* __restrict__ be2, const float* __restrict__ Wg1,
    const float* __restrict__ dinv, __half* __restrict__ hws1, __half* __restrict__ hws2) {
    __shared__ float sWe1[6 * 64];
    __shared__ float sbe1[64];
    __shared__ float sWe2[64 * 32];
    __shared__ float sbe2[32];
    __shared__ float sWg1[32 * 32];
    for (int i = threadIdx.x; i < 6 * 64; i += 256) sWe1[i] = We1[i];
    for (int i = threadIdx.x; i < 64; i += 256) sbe1[i] = be1[i];
    for (int i = threadIdx.x; i < 64 * 32; i += 256) sWe2[i] = We2[i];
    for (int i = threadIdx.x; i < 32; i += 256) sbe2[i] = be2[i];
    for (int i = threadIdx.x; i < 32 * 32; i += 256) sWg1[i] = Wg1[i];
    __syncthreads();

    int node = blockIdx.x * 256 + threadIdx.x;
    if (node > NN) return;
    if (node == NN) {  // zero pad rows for DUMMY src
        for (int j = 0; j < 32; j++) {
            hws1[(size_t)NN * 32 + j] = __float2half(0.f);
            hws2[(size_t)NN * 32 + j] = __float2half(0.f);
        }
        return;
    }

    float xv[6];
#pragma unroll
    for (int k = 0; k < 6; k++) xv[k] = x[node * 6 + k];

    float h1[64];
#pragma unroll
    for (int j = 0; j < 64; j++) {
        float a = sbe1[j];
#pragma unroll
        for (int k = 0; k < 6; k++) a += xv[k] * sWe1[k * 64 + j];
        h1[j] = tanhf(a);
    }

    float h[32];
#pragma unroll 4
    for (int j = 0; j < 32; j++) {
        float a = sbe2[j];
#pragma unroll
        for (int k = 0; k < 64; k++) a += h1[k] * sWe2[k * 32 + j];
        h[j] = tanhf(a);
    }

    float di = dinv[node];
    __half* o = hws1 + (size_t)node * 32;
#pragma unroll 4
    for (int j = 0; j < 32; j++) {
        float a = 0.f;
#pragma unroll
        for (int k = 0; k < 32; k++) a += h[k] * sWg1[k * 32 + j];
        o[j] = __float2half(a * di);
    }
}

// ---- gather1: persistent waves, W in VGPRs, no LDS. conv1 + (relu @ Wg2)*dinv ----
__global__ __launch_bounds__(256) void gather1_kernel(
    const unsigned int* __restrict__ sorted, const unsigned int* __restrict__ rsd,
    const float* __restrict__ dinv, const __half* __restrict__ hws1,
    const float* __restrict__ bg1, const float* __restrict__ Wg2,
    __half* __restrict__ hws2) {
    int lane = threadIdx.x & 63;
    int g = lane >> 4;   // edge group 0..3
    int p = lane & 15;   // feature pair
    int f = lane & 31;   // feature (epilogue)
    float wreg[32];
#pragma unroll
    for (int k = 0; k < 32; k++) wreg[k] = Wg2[k * 32 + f];  // column f in regs
    float bf = bg1[f];
    int wave = (blockIdx.x * 256 + threadIdx.x) >> 6;
    const __half2* H = (const __half2*)hws1;
    for (int node = wave; node < NN; node += GWAVES) {
        unsigned int r = rsd[node];
        unsigned int base = r & 0x3FFFFFu;
        unsigned int d = (r >> 22) << 4;
        float ax = 0.f, ay = 0.f;
        for (unsigned int k = g; k < d; k += 16) {  // 16 rows in flight per wave
            unsigned int s0 = sorted[base + k];
            unsigned int s1 = sorted[base + k + 4];
            unsigned int s2 = sorted[base + k + 8];
            unsigned int s3 = sorted[base + k + 12];
            float2 v0 = __half22float2(H[(size_t)s0 * 16 + p]);
            float2 v1 = __half22float2(H[(size_t)s1 * 16 + p]);
            float2 v2 = __half22float2(H[(size_t)s2 * 16 + p]);
            float2 v3 = __half22float2(H[(size_t)s3 * 16 + p]);
            ax += (v0.x + v1.x) + (v2.x + v3.x);
            ay += (v0.y + v1.y) + (v2.y + v3.y);
        }
        ax += __shfl_xor(ax, 16); ay += __shfl_xor(ay, 16);
        ax += __shfl_xor(ax, 32); ay += __shfl_xor(ay, 32);
        float2 sv = __half22float2(H[(size_t)node * 16 + p]);  // self-loop
        ax += sv.x; ay += sv.y;
        float ae = __shfl(ax, f >> 1);
        float ao = __shfl(ay, f >> 1);
        float av = (f & 1) ? ao : ae;
        float di = dinv[node];
        float h = di * av + bf;
        h = h > 0.f ? h : 0.f;
        float o = 0.f;
#pragma unroll
        for (int k = 0; k < 32; k++) o += __shfl(h, k) * wreg[k];
        if (lane < 32) hws2[(size_t)node * 32 + f] = __float2half(o * di);
    }
}

// ---- gather2: persistent waves, conv2 + prediction MLP ----
__global__ __launch_bounds__(256) void gather2_kernel(
    const unsigned int* __restrict__ sorted, const unsigned int* __restrict__ rsd,
    const float* __restrict__ dinv, const __half* __restrict__ hws2,
    const float* __restrict__ bg2, const float* __restrict__ Wp1,
    const float* __restrict__ bp1, const float* __restrict__ Wp2,
    const float* __restrict__ bp2, float* __restrict__ out) {
    int lane = threadIdx.x & 63;
    int g = lane >> 4;
    int p = lane & 15;
    int f = lane & 31;
    float wreg[32];
#pragma unroll
    for (int k = 0; k < 32; k++) wreg[k] = Wp1[k * 32 + f];
    float bgf = bg2[f];
    float b1f = bp1[f];
    float w2f = Wp2[f];
    float b2 = bp2[0];
    int wave = (blockIdx.x * 256 + threadIdx.x) >> 6;
    const __half2* H = (const __half2*)hws2;
    for (int node = wave; node < NN; node += GWAVES) {
        unsigned int r = rsd[node];
        unsigned int base = r & 0x3FFFFFu;
        unsigned int d = (r >> 22) << 4;
        float ax = 0.f, ay = 0.f;
        for (unsigned int k = g; k < d; k += 16) {
            unsigned int s0 = sorted[base + k];
            unsigned int s1 = sorted[base + k + 4];
            unsigned int s2 = sorted[base + k + 8];
            unsigned int s3 = sorted[base + k + 12];
            float2 v0 = __half22float2(H[(size_t)s0 * 16 + p]);
            float2 v1 = __half22float2(H[(size_t)s1 * 16 + p]);
            float2 v2 = __half22float2(H[(size_t)s2 * 16 + p]);
            float2 v3 = __half22float2(H[(size_t)s3 * 16 + p]);
            ax += (v0.x + v1.x) + (v2.x + v3.x);
            ay += (v0.y + v1.y) + (v2.y + v3.y);
        }
        ax += __shfl_xor(ax, 16); ay += __shfl_xor(ay, 16);
        ax += __shfl_xor(ax, 32); ay += __shfl_xor(ay, 32);
        float2 sv = __half22float2(H[(size_t)node * 16 + p]);
        ax += sv.x; ay += sv.y;
        float ae = __shfl(ax, f >> 1);
        float ao = __shfl(ay, f >> 1);
        float av = (f & 1) ? ao : ae;
        float di = dinv[node];
        float h = di * av + bgf;
        h = h > 0.f ? h : 0.f;
        float pre = b1f;
#pragma unroll
        for (int k = 0; k < 32; k++) pre += __shfl(h, k) * wreg[k];
        float t = tanhf(pre) * w2f;
#pragma unroll
        for (int off = 1; off < 32; off <<= 1) t += __shfl_xor(t, off);
        if (lane == 0) out[node] = tanhf(t + b2);
    }
}

extern "C" void kernel_launch(void* const* d_in, const int* in_sizes, int n_in,
                              void* d_out, int out_size, void* d_ws, size_t ws_size,
                              hipStream_t stream) {
    const float* x = (const float*)d_in[0];
    const int* edge = (const int*)d_in[1];  // [2, NE] int32
    const int* src = edge;
    const int* dst = edge + NE;
    const float* We1 = (const float*)d_in[2];
    const float* be1 = (const float*)d_in[3];
    const float* We2 = (const float*)d_in[4];
    const float* be2 = (const float*)d_in[5];
    const float* Wg1 = (const float*)d_in[6];
    const float* bg1 = (const float*)d_in[7];
    const float* Wg2 = (const float*)d_in[8];
    const float* bg2 = (const float*)d_in[9];
    const float* Wp1 = (const float*)d_in[10];
    const float* bp1 = (const float*)d_in[11];
    const float* Wp2 = (const float*)d_in[12];
    const float* bp2 = (const float*)d_in[13];
    float* out = (float*)d_out;

    // workspace (4B units):
    // bcount[1024] | dinv[NN] | rsd[NN] | packed[NBUCK*CAP] | hws1 | hws2
    unsigned int* bcount = (unsigned int*)d_ws;
    float* dinv = (float*)d_ws + 1024;
    unsigned int* rsd = (unsigned int*)d_ws + 1024 + NN;
    unsigned int* packed = (unsigned int*)d_ws + 1024 + 2 * NN;
    __half* hws1 = (__half*)((unsigned int*)d_ws + 1024 + 2 * NN + NBUCK * CAP);
    __half* hws2 = hws1 + (size_t)(NN + 1) * 32;

    hipMemsetAsync(bcount, 0, 1024 * sizeof(unsigned int), stream);

    int gridN = (NN + 256) / 256;       // covers node NN (pad-row writer)

    part_kernel<<<PBLOCKS, PTPB, 0, stream>>>(src, dst, bcount, packed);
    sort_kernel<<<NBUCK, 256, 0, stream>>>(bcount, packed, rsd, dinv);
    embed_kernel<<<gridN, 256, 0, stream>>>(x, We1, be1, We2, be2, Wg1, dinv, hws1, hws2);
    gather1_kernel<<<GBLK, 256, 0, stream>>>(packed, rsd, dinv, hws1, bg1, Wg2, hws2);
    gather2_kernel<<<GBLK, 256, 0, stream>>>(packed, rsd, dinv, hws2, bg2, Wp1, bp1, Wp2, bp2, out);
}

// Round 12
// 245.959 us; speedup vs baseline: 3.7028x; 1.1340x over previous
//
#include <hip/hip_runtime.h>
#include <hip/hip_fp16.h>

#define NN 100000
#define NE 1600000
#define NPB 128                        // nodes per bucket
#define NBUCK ((NN + NPB - 1) / NPB)   // 782
#define CAP 4608                       // reserved slots per bucket (mean ~2950 incl slack)
#define PBLOCKS 256
#define PTPB 512
#define EPB (NE / PBLOCKS)             // 6250
#define DUMMY 100000u                  // pad src: hws row NN is all-zero
#define SENT 0xFFFFFFFFu               // reservation-slack sentinel
#define GBLK 4096                      // gather blocks
#define NSLOT (GBLK * 8)               // 32768 half-wave slots (2 nodes per wave)

// ---- bucket partition, 32B-aligned per-(block,bucket) runs: packed = (dst&127)<<17 | src ----
__global__ __launch_bounds__(PTPB) void part_kernel(const int* __restrict__ src,
                                                    const int* __restrict__ dst,
                                                    unsigned int* __restrict__ bcount,
                                                    unsigned int* __restrict__ packed) {
    __shared__ unsigned int lcnt[NBUCK];
    __shared__ unsigned int lcur[NBUCK];
    __shared__ unsigned int lend[NBUCK];
    for (int i = threadIdx.x; i < NBUCK; i += PTPB) lcnt[i] = 0u;
    __syncthreads();
    int e0 = blockIdx.x * EPB;
    for (int e = e0 + threadIdx.x; e < e0 + EPB; e += PTPB)
        atomicAdd(&lcnt[((unsigned)dst[e]) >> 7], 1u);
    __syncthreads();
    for (int i = threadIdx.x; i < NBUCK; i += PTPB) {
        unsigned int c = lcnt[i];
        unsigned int rc = (c + 7u) & ~7u;                // 32B-aligned reservation
        unsigned int base = rc ? atomicAdd(&bcount[i], rc) : 0u;
        lcur[i] = base;
        lend[i] = base + rc;
    }
    __syncthreads();
    for (int e = e0 + threadIdx.x; e < e0 + EPB; e += PTPB) {
        unsigned int d = (unsigned)dst[e];
        unsigned int b = d >> 7;
        unsigned int pos = atomicAdd(&lcur[b], 1u);
        packed[(size_t)b * CAP + pos] = ((d & 127u) << 17) | (unsigned)src[e];
    }
    __syncthreads();
    for (int i = threadIdx.x; i < NBUCK; i += PTPB)      // fill slack with sentinel
        for (unsigned int j = lcur[i]; j < lend[i]; j++)
            packed[(size_t)i * CAP + j] = SENT;
}

// ---- per-bucket counting sort (skip sentinels), pad node lists to mult of 8 ----
// writes rsd[node] = row_start | (padded_deg/8)<<22  and dinv[node]
__global__ __launch_bounds__(512) void sort_kernel(const unsigned int* __restrict__ bcount,
                                                   unsigned int* __restrict__ packed,
                                                   unsigned int* __restrict__ rsd,
                                                   float* __restrict__ dinv) {
    __shared__ unsigned int lraw[CAP];
    __shared__ unsigned int lsort[CAP];
    __shared__ unsigned int cnt[NPB];
    __shared__ unsigned int ps[NPB];   // inclusive prefix of PADDED counts
    __shared__ unsigned int cur[NPB];
    __shared__ unsigned int ntot;
    int b = blockIdx.x;
    int tid = threadIdx.x;
    if (tid < NPB) cnt[tid] = 0u;
    __syncthreads();
    unsigned int n = bcount[b];        // reserved total (includes sentinel holes)
    unsigned int* pk = packed + (size_t)b * CAP;
    for (unsigned int i = tid; i < n; i += 512) {
        unsigned int p = pk[i];
        lraw[i] = p;
        if (p != SENT) atomicAdd(&cnt[p >> 17], 1u);
    }
    __syncthreads();
    if (tid < NPB) ps[tid] = (cnt[tid] + 7u) & ~7u;  // padded count
    __syncthreads();
    for (int off = 1; off < NPB; off <<= 1) {
        unsigned int t = (tid < NPB && tid >= off) ? ps[tid - off] : 0u;
        __syncthreads();
        if (tid < NPB) ps[tid] += t;
        __syncthreads();
    }
    if (tid == NPB - 1) ntot = ps[NPB - 1];
    __syncthreads();
    unsigned int np = ntot;
    for (unsigned int i = tid; i < np; i += 512) lsort[i] = DUMMY;
    if (tid < NPB) cur[tid] = ps[tid] - ((cnt[tid] + 7u) & ~7u);
    __syncthreads();
    for (unsigned int i = tid; i < n; i += 512) {
        unsigned int p = lraw[i];
        if (p != SENT) {
            unsigned int pos = atomicAdd(&cur[p >> 17], 1u);
            lsort[pos] = p & 0x1FFFFu;
        }
    }
    __syncthreads();
    for (unsigned int i = tid; i < np; i += 512) pk[i] = lsort[i];
    if (tid < NPB) {
        int node = b * NPB + tid;
        if (node < NN) {
            unsigned int c = cnt[tid];
            unsigned int pc = (c + 7u) & ~7u;
            unsigned int rs = (unsigned int)(b * CAP) + ps[tid] - pc;  // < 2^22
            rsd[node] = rs | ((pc >> 3) << 22);
            dinv[node] = rsqrtf((float)c + 1.0f);   // real deg + self-loop
        }
    }
}

// ---------------- embed MLP + hws1 = fp16((h @ Wg1) * dinv); zeros pad row NN ----------------
__global__ __launch_bounds__(256) void embed_kernel(
    const float* __restrict__ x, const float* __restrict__ We1, const float* __restrict__ be1,
    const float* __restrict__ We2, const float* __restrict__ be2, const float* __restrict__ Wg1,
    const float* __restrict__ dinv, __half* __restrict__ hws1, __half* __restrict__ hws2) {
    __shared__ float sWe1[6 * 64];
    __shared__ float sbe1[64];
    __shared__ float sWe2[64 * 32];
    __shared__ float sbe2[32];
    __shared__ float sWg1[32 * 32];
    for (int i = threadIdx.x; i < 6 * 64; i += 256) sWe1[i] = We1[i];
    for (int i = threadIdx.x; i < 64; i += 256) sbe1[i] = be1[i];
    for (int i = threadIdx.x; i < 64 * 32; i += 256) sWe2[i] = We2[i];
    for (int i = threadIdx.x; i < 32; i += 256) sbe2[i] = be2[i];
    for (int i = threadIdx.x; i < 32 * 32; i += 256) sWg1[i] = Wg1[i];
    __syncthreads();

    int node = blockIdx.x * 256 + threadIdx.x;
    if (node > NN) return;
    if (node == NN) {  // zero pad rows for DUMMY src
        for (int j = 0; j < 32; j++) {
            hws1[(size_t)NN * 32 + j] = __float2half(0.f);
            hws2[(size_t)NN * 32 + j] = __float2half(0.f);
        }
        return;
    }

    float xv[6];
#pragma unroll
    for (int k = 0; k < 6; k++) xv[k] = x[node * 6 + k];

    float h1[64];
#pragma unroll
    for (int j = 0; j < 64; j++) {
        float a = sbe1[j];
#pragma unroll
        for (int k = 0; k < 6; k++) a += xv[k] * sWe1[k * 64 + j];
        h1[j] = tanhf(a);
    }

    float h[32];
#pragma unroll 4
    for (int j = 0; j < 32; j++) {
        float a = sbe2[j];
#pragma unroll
        for (int k = 0; k < 64; k++) a += h1[k] * sWe2[k * 32 + j];
        h[j] = tanhf(a);
    }

    float di = dinv[node];
    __half* o = hws1 + (size_t)node * 32;
#pragma unroll 4
    for (int j = 0; j < 32; j++) {
        float a = 0.f;
#pragma unroll
        for (int k = 0; k < 32; k++) a += h[k] * sWg1[k * 32 + j];
        o[j] = __float2half(a * di);
    }
}

// ---- gather1: 2 nodes per wave (32 lanes each), W in VGPRs, no LDS ----
__global__ __launch_bounds__(256) void gather1_kernel(
    const unsigned int* __restrict__ sorted, const unsigned int* __restrict__ rsd,
    const float* __restrict__ dinv, const __half* __restrict__ hws1,
    const float* __restrict__ bg1, const float* __restrict__ Wg2,
    __half* __restrict__ hws2) {
    int lane = threadIdx.x & 31;  // lane within half-wave
    int g = lane >> 4;            // edge group 0..1
    int p = lane & 15;            // feature pair
    int f = lane;                 // feature (epilogue)
    float wreg[32];
#pragma unroll
    for (int k = 0; k < 32; k++) wreg[k] = Wg2[k * 32 + f];  // column f in regs
    float bf = bg1[f];
    int slot = (blockIdx.x * 256 + threadIdx.x) >> 5;  // half-wave id
    const __half2* H = (const __half2*)hws1;
    for (int node = slot; node < NN; node += NSLOT) {
        unsigned int r = rsd[node];
        unsigned int base = r & 0x3FFFFFu;
        unsigned int d = (r >> 22) << 3;
        float ax = 0.f, ay = 0.f;
        for (unsigned int k = g * 4; k < d; k += 8) {  // 8 rows/node in flight
            uint4 s4 = *reinterpret_cast<const uint4*>(sorted + base + k);
            float2 v0 = __half22float2(H[(size_t)s4.x * 16 + p]);
            float2 v1 = __half22float2(H[(size_t)s4.y * 16 + p]);
            float2 v2 = __half22float2(H[(size_t)s4.z * 16 + p]);
            float2 v3 = __half22float2(H[(size_t)s4.w * 16 + p]);
            ax += (v0.x + v1.x) + (v2.x + v3.x);
            ay += (v0.y + v1.y) + (v2.y + v3.y);
        }
        ax += __shfl_xor(ax, 16); ay += __shfl_xor(ay, 16);  // combine 2 groups
        float2 sv = __half22float2(H[(size_t)node * 16 + p]);  // self-loop
        ax += sv.x; ay += sv.y;
        float ae = __shfl(ax, f >> 1, 32);
        float ao = __shfl(ay, f >> 1, 32);
        float av = (f & 1) ? ao : ae;
        float di = dinv[node];
        float h = di * av + bf;
        h = h > 0.f ? h : 0.f;
        float o = 0.f;
#pragma unroll
        for (int k = 0; k < 32; k++) o += __shfl(h, k, 32) * wreg[k];
        hws2[(size_t)node * 32 + f] = __float2half(o * di);
    }
}

// ---- gather2: 2 nodes per wave, conv2 + prediction MLP ----
__global__ __launch_bounds__(256) void gather2_kernel(
    const unsigned int* __restrict__ sorted, const unsigned int* __restrict__ rsd,
    const float* __restrict__ dinv, const __half* __restrict__ hws2,
    const float* __restrict__ bg2, const float* __restrict__ Wp1,
    const float* __restrict__ bp1, const float* __restrict__ Wp2,
    const float* __restrict__ bp2, float* __restrict__ out) {
    int lane = threadIdx.x & 31;
    int g = lane >> 4;
    int p = lane & 15;
    int f = lane;
    float wreg[32];
#pragma unroll
    for (int k = 0; k < 32; k++) wreg[k] = Wp1[k * 32 + f];
    float bgf = bg2[f];
    float b1f = bp1[f];
    float w2f = Wp2[f];
    float b2 = bp2[0];
    int slot = (blockIdx.x * 256 + threadIdx.x) >> 5;
    const __half2* H = (const __half2*)hws2;
    for (int node = slot; node < NN; node += NSLOT) {
        unsigned int r = rsd[node];
        unsigned int base = r & 0x3FFFFFu;
        unsigned int d = (r >> 22) << 3;
        float ax = 0.f, ay = 0.f;
        for (unsigned int k = g * 4; k < d; k += 8) {
            uint4 s4 = *reinterpret_cast<const uint4*>(sorted + base + k);
            float2 v0 = __half22float2(H[(size_t)s4.x * 16 + p]);
            float2 v1 = __half22float2(H[(size_t)s4.y * 16 + p]);
            float2 v2 = __half22float2(H[(size_t)s4.z * 16 + p]);
            float2 v3 = __half22float2(H[(size_t)s4.w * 16 + p]);
            ax += (v0.x + v1.x) + (v2.x + v3.x);
            ay += (v0.y + v1.y) + (v2.y + v3.y);
        }
        ax += __shfl_xor(ax, 16); ay += __shfl_xor(ay, 16);
        float2 sv = __half22float2(H[(size_t)node * 16 + p]);
        ax += sv.x; ay += sv.y;
        float ae = __shfl(ax, f >> 1, 32);
        float ao = __shfl(ay, f >> 1, 32);
        float av = (f & 1) ? ao : ae;
        float di = dinv[node];
        float h = di * av + bgf;
        h = h > 0.f ? h : 0.f;
        float pre = b1f;
#pragma unroll
        for (int k = 0; k < 32; k++) pre += __shfl(h, k, 32) * wreg[k];
        float t = tanhf(pre) * w2f;
#pragma unroll
        for (int off = 1; off < 32; off <<= 1) t += __shfl_xor(t, off);
        if (lane == 0) out[node] = tanhf(t + b2);
    }
}

extern "C" void kernel_launch(void* const* d_in, const int* in_sizes, int n_in,
                              void* d_out, int out_size, void* d_ws, size_t ws_size,
                              hipStream_t stream) {
    const float* x = (const float*)d_in[0];
    const int* edge = (const int*)d_in[1];  // [2, NE] int32
    const int* src = edge;
    const int* dst = edge + NE;
    const float* We1 = (const float*)d_in[2];
    const float* be1 = (const float*)d_in[3];
    const float* We2 = (const float*)d_in[4];
    const float* be2 = (const float*)d_in[5];
    const float* Wg1 = (const float*)d_in[6];
    const float* bg1 = (const float*)d_in[7];
    const float* Wg2 = (const float*)d_in[8];
    const float* bg2 = (const float*)d_in[9];
    const float* Wp1 = (const float*)d_in[10];
    const float* bp1 = (const float*)d_in[11];
    const float* Wp2 = (const float*)d_in[12];
    const float* bp2 = (const float*)d_in[13];
    float* out = (float*)d_out;

    // workspace (4B units):
    // bcount[1024] | dinv[NN] | rsd[NN] | packed[NBUCK*CAP] | hws1 | hws2
    unsigned int* bcount = (unsigned int*)d_ws;
    float* dinv = (float*)d_ws + 1024;
    unsigned int* rsd = (unsigned int*)d_ws + 1024 + NN;
    unsigned int* packed = (unsigned int*)d_ws + 1024 + 2 * NN;
    __half* hws1 = (__half*)((unsigned int*)d_ws + 1024 + 2 * NN + NBUCK * CAP);
    __half* hws2 = hws1 + (size_t)(NN + 1) * 32;

    hipMemsetAsync(bcount, 0, 1024 * sizeof(unsigned int), stream);

    int gridN = (NN + 256) / 256;       // covers node NN (pad-row writer)

    part_kernel<<<PBLOCKS, PTPB, 0, stream>>>(src, dst, bcount, packed);
    sort_kernel<<<NBUCK, 512, 0, stream>>>(bcount, packed, rsd, dinv);
    embed_kernel<<<gridN, 256, 0, stream>>>(x, We1, be1, We2, be2, Wg1, dinv, hws1, hws2);
    gather1_kernel<<<GBLK, 256, 0, stream>>>(packed, rsd, dinv, hws1, bg1, Wg2, hws2);
    gather2_kernel<<<GBLK, 256, 0, stream>>>(packed, rsd, dinv, hws2, bg2, Wp1, bp1, Wp2, bp2, out);
}